// Round 1
// baseline (10666.033 us; speedup 1.0000x reference)
//
#include <hip/hip_runtime.h>
#include <hip/hip_bf16.h>

// LSMPool: T=128 sequential LIF-reservoir steps (fc1: [64x5120]@[5120x4096]^T
// with binary spike A), then parallel readout GEMM (8192x4096 @ 4096x512^T)
// + readout LIF scan. Round 1 = correctness-first baseline:
//   - w1/w2 converted to split bf16 (hi+lo) so MFMA approximates fp32.
//   - 128 per-step kernels sequenced by stream order (no coop launch yet).
//   - Simple single-buffered LDS GEMM (2 barriers / K-step), 16x16x32 MFMA.
// ws layout (bytes, 256-aligned):
//   w1hi 41.9M | w1lo 41.9M | xb 16.8M | spk 67.6M ((T+1)*B*HID bf16,
//   slot0 = zeros) | w2hi 4.2M | w2lo 4.2M | mem1 1.0M | cur2 16.8M
//   total ~186 MiB.

namespace {
constexpr int T_STEPS = 128;
constexpr int BATCH   = 64;
constexpr int IN_F    = 1024;
constexpr int HID     = 4096;
constexpr int OUT_F   = 512;
constexpr int TOTAL   = IN_F + HID;  // 5120
}

using bf16x8 = __attribute__((ext_vector_type(8))) short;   // 8 bf16 (4 VGPRs)
using f32x4  = __attribute__((ext_vector_type(4))) float;   // MFMA acc

// ---------------- prep kernels ----------------

// fp32 -> (hi, lo) bf16 split: hi = bf16(w), lo = bf16(w - float(hi)).
__global__ void k_cvt_split(const float* __restrict__ src,
                            __hip_bfloat16* __restrict__ hi,
                            __hip_bfloat16* __restrict__ lo, int n4) {
  int i = blockIdx.x * blockDim.x + threadIdx.x;
  if (i >= n4) return;
  float4 v = reinterpret_cast<const float4*>(src)[i];
#define CVT1(J, F)                                                        \
  {                                                                       \
    __hip_bfloat16 hb = __float2bfloat16(F);                              \
    hi[4 * (size_t)i + J] = hb;                                           \
    lo[4 * (size_t)i + J] = __float2bfloat16((F) - __bfloat162float(hb)); \
  }
  CVT1(0, v.x) CVT1(1, v.y) CVT1(2, v.z) CVT1(3, v.w)
#undef CVT1
}

// x (exact {0,1}) -> bf16
__global__ void k_cvt_x(const float* __restrict__ src,
                        __hip_bfloat16* __restrict__ dst, int n) {
  int i = blockIdx.x * blockDim.x + threadIdx.x;
  if (i >= n) return;
  dst[i] = __float2bfloat16(src[i]);
}

// zero mem1 (f32) and spk slot 0 (bf16), both B*HID elements
__global__ void k_zero(float* __restrict__ mem1, ushort* __restrict__ spk0, int n) {
  int i = blockIdx.x * blockDim.x + threadIdx.x;
  if (i >= n) return;
  mem1[i] = 0.0f;
  spk0[i] = 0;  // bf16 +0.0
}

// ---------------- fused fc1 GEMM + LIF step ----------------
// grid = HID/64 = 64 blocks, 256 threads (4 waves). Block owns N-slice of 64
// hidden units, all 64 batch rows. Wave w owns n-sub [w*16, w*16+16), loops
// 4 M-fragments. K-loop over TOTAL=5120 in steps of 32; hi and lo B-tiles
// accumulate into the SAME acc (sum is linear).
__global__ __launch_bounds__(256)
void k_lsm_step(int t,
                const __hip_bfloat16* __restrict__ xb,    // [T][B][IN_F]
                __hip_bfloat16* __restrict__ spk,         // [T+1][B][HID]
                const __hip_bfloat16* __restrict__ w1hi,  // [HID][TOTAL]
                const __hip_bfloat16* __restrict__ w1lo,
                float* __restrict__ mem1,                 // [B][HID]
                const float* __restrict__ beta,           // [HID]
                const float* __restrict__ thr) {          // [HID]
  __shared__ __align__(16) short lA[64 * 32];
  __shared__ __align__(16) short lBh[64 * 32];
  __shared__ __align__(16) short lBl[64 * 32];

  const int tid  = threadIdx.x;
  const int lane = tid & 63;
  const int w    = tid >> 6;
  const int nbase = blockIdx.x * 64;

  const __hip_bfloat16* xt      = xb  + (size_t)t * BATCH * IN_F;
  const __hip_bfloat16* spk_in  = spk + (size_t)t * BATCH * HID;
  __hip_bfloat16*       spk_out = spk + (size_t)(t + 1) * BATCH * HID;

  f32x4 acc0 = {0.f, 0.f, 0.f, 0.f};
  f32x4 acc1 = {0.f, 0.f, 0.f, 0.f};
  f32x4 acc2 = {0.f, 0.f, 0.f, 0.f};
  f32x4 acc3 = {0.f, 0.f, 0.f, 0.f};

  const int r  = tid >> 2;        // staging row 0..63
  const int kc = (tid & 3) * 8;   // staging k-chunk (8 bf16)

  const int fr = lane & 15;        // fragment row index
  const int fk = (lane >> 4) * 8;  // fragment k offset

  for (int kt = 0; kt < TOTAL / 32; ++kt) {
    const int k0 = kt * 32;
    __syncthreads();  // protect LDS from previous iteration's readers
    // stage A (spike matrix): cols [0,1024) from x_t, [1024,5120) from spk_in
    bf16x8 av;
    if (k0 < IN_F) {
      av = *reinterpret_cast<const bf16x8*>(xt + (size_t)r * IN_F + k0 + kc);
    } else {
      av = *reinterpret_cast<const bf16x8*>(spk_in + (size_t)r * HID + (k0 - IN_F) + kc);
    }
    *reinterpret_cast<bf16x8*>(&lA[r * 32 + kc]) = av;
    // stage B (w1 rows = output units; already N-major-K layout)
    bf16x8 bh = *reinterpret_cast<const bf16x8*>(w1hi + (size_t)(nbase + r) * TOTAL + k0 + kc);
    bf16x8 bl = *reinterpret_cast<const bf16x8*>(w1lo + (size_t)(nbase + r) * TOTAL + k0 + kc);
    *reinterpret_cast<bf16x8*>(&lBh[r * 32 + kc]) = bh;
    *reinterpret_cast<bf16x8*>(&lBl[r * 32 + kc]) = bl;
    __syncthreads();

    bf16x8 fbh = *reinterpret_cast<const bf16x8*>(&lBh[(w * 16 + fr) * 32 + fk]);
    bf16x8 fbl = *reinterpret_cast<const bf16x8*>(&lBl[(w * 16 + fr) * 32 + fk]);
    bf16x8 fa0 = *reinterpret_cast<const bf16x8*>(&lA[(0 * 16 + fr) * 32 + fk]);
    bf16x8 fa1 = *reinterpret_cast<const bf16x8*>(&lA[(1 * 16 + fr) * 32 + fk]);
    bf16x8 fa2 = *reinterpret_cast<const bf16x8*>(&lA[(2 * 16 + fr) * 32 + fk]);
    bf16x8 fa3 = *reinterpret_cast<const bf16x8*>(&lA[(3 * 16 + fr) * 32 + fk]);

    acc0 = __builtin_amdgcn_mfma_f32_16x16x32_bf16(fa0, fbh, acc0, 0, 0, 0);
    acc0 = __builtin_amdgcn_mfma_f32_16x16x32_bf16(fa0, fbl, acc0, 0, 0, 0);
    acc1 = __builtin_amdgcn_mfma_f32_16x16x32_bf16(fa1, fbh, acc1, 0, 0, 0);
    acc1 = __builtin_amdgcn_mfma_f32_16x16x32_bf16(fa1, fbl, acc1, 0, 0, 0);
    acc2 = __builtin_amdgcn_mfma_f32_16x16x32_bf16(fa2, fbh, acc2, 0, 0, 0);
    acc2 = __builtin_amdgcn_mfma_f32_16x16x32_bf16(fa2, fbl, acc2, 0, 0, 0);
    acc3 = __builtin_amdgcn_mfma_f32_16x16x32_bf16(fa3, fbh, acc3, 0, 0, 0);
    acc3 = __builtin_amdgcn_mfma_f32_16x16x32_bf16(fa3, fbl, acc3, 0, 0, 0);
  }

  // Epilogue + LIF. C/D layout (m89): col = lane&15 (n), row = (lane>>4)*4+q (batch).
  const int n   = nbase + w * 16 + (lane & 15);
  const float bt = beta[n];
  const float th = thr[n];
  const int brow = (lane >> 4) * 4;

#define LIF_EPI(ACC, M)                                    \
  {                                                        \
    _Pragma("unroll")                                      \
    for (int q = 0; q < 4; ++q) {                          \
      const int b = (M) * 16 + brow + q;                   \
      const size_t idx = (size_t)b * HID + n;              \
      float mv = mem1[idx];                                \
      mv = mv - bt + (ACC)[q];                             \
      mv = fmaxf(mv, 0.0f);         /* state_quant=relu */ \
      const float s = (mv > th) ? 1.0f : 0.0f;             \
      mv -= s * th;                 /* reset by subtract */ \
      mem1[idx] = mv;                                      \
      spk_out[idx] = __float2bfloat16(s);                  \
    }                                                      \
  }
  LIF_EPI(acc0, 0)
  LIF_EPI(acc1, 1)
  LIF_EPI(acc2, 2)
  LIF_EPI(acc3, 3)
#undef LIF_EPI
}

// ---------------- readout GEMM: cur2 = spk_rec @ w2^T + b2 ----------------
// M = T*B = 8192, N = OUT_F = 512, K = HID = 4096. grid = 128*8 = 1024 blocks.
__global__ __launch_bounds__(256)
void k_ro_gemm(const __hip_bfloat16* __restrict__ A,      // [8192][HID] (spk slots 1..T)
               const __hip_bfloat16* __restrict__ w2hi,   // [OUT_F][HID]
               const __hip_bfloat16* __restrict__ w2lo,
               const float* __restrict__ b2,              // [OUT_F]
               float* __restrict__ cur2) {                // [8192][OUT_F]
  __shared__ __align__(16) short lA[64 * 32];
  __shared__ __align__(16) short lBh[64 * 32];
  __shared__ __align__(16) short lBl[64 * 32];

  const int tid  = threadIdx.x;
  const int lane = tid & 63;
  const int w    = tid >> 6;
  const int mt = blockIdx.x >> 3;   // 0..127
  const int nt = blockIdx.x & 7;    // 0..7
  const int mbase = mt * 64;
  const int nbase = nt * 64;

  f32x4 acc0 = {0.f, 0.f, 0.f, 0.f};
  f32x4 acc1 = {0.f, 0.f, 0.f, 0.f};
  f32x4 acc2 = {0.f, 0.f, 0.f, 0.f};
  f32x4 acc3 = {0.f, 0.f, 0.f, 0.f};

  const int r  = tid >> 2;
  const int kc = (tid & 3) * 8;
  const int fr = lane & 15;
  const int fk = (lane >> 4) * 8;

  for (int kt = 0; kt < HID / 32; ++kt) {
    const int k0 = kt * 32;
    __syncthreads();
    bf16x8 av = *reinterpret_cast<const bf16x8*>(A    + (size_t)(mbase + r) * HID + k0 + kc);
    bf16x8 bh = *reinterpret_cast<const bf16x8*>(w2hi + (size_t)(nbase + r) * HID + k0 + kc);
    bf16x8 bl = *reinterpret_cast<const bf16x8*>(w2lo + (size_t)(nbase + r) * HID + k0 + kc);
    *reinterpret_cast<bf16x8*>(&lA[r * 32 + kc])  = av;
    *reinterpret_cast<bf16x8*>(&lBh[r * 32 + kc]) = bh;
    *reinterpret_cast<bf16x8*>(&lBl[r * 32 + kc]) = bl;
    __syncthreads();

    bf16x8 fbh = *reinterpret_cast<const bf16x8*>(&lBh[(w * 16 + fr) * 32 + fk]);
    bf16x8 fbl = *reinterpret_cast<const bf16x8*>(&lBl[(w * 16 + fr) * 32 + fk]);
    bf16x8 fa0 = *reinterpret_cast<const bf16x8*>(&lA[(0 * 16 + fr) * 32 + fk]);
    bf16x8 fa1 = *reinterpret_cast<const bf16x8*>(&lA[(1 * 16 + fr) * 32 + fk]);
    bf16x8 fa2 = *reinterpret_cast<const bf16x8*>(&lA[(2 * 16 + fr) * 32 + fk]);
    bf16x8 fa3 = *reinterpret_cast<const bf16x8*>(&lA[(3 * 16 + fr) * 32 + fk]);

    acc0 = __builtin_amdgcn_mfma_f32_16x16x32_bf16(fa0, fbh, acc0, 0, 0, 0);
    acc0 = __builtin_amdgcn_mfma_f32_16x16x32_bf16(fa0, fbl, acc0, 0, 0, 0);
    acc1 = __builtin_amdgcn_mfma_f32_16x16x32_bf16(fa1, fbh, acc1, 0, 0, 0);
    acc1 = __builtin_amdgcn_mfma_f32_16x16x32_bf16(fa1, fbl, acc1, 0, 0, 0);
    acc2 = __builtin_amdgcn_mfma_f32_16x16x32_bf16(fa2, fbh, acc2, 0, 0, 0);
    acc2 = __builtin_amdgcn_mfma_f32_16x16x32_bf16(fa2, fbl, acc2, 0, 0, 0);
    acc3 = __builtin_amdgcn_mfma_f32_16x16x32_bf16(fa3, fbh, acc3, 0, 0, 0);
    acc3 = __builtin_amdgcn_mfma_f32_16x16x32_bf16(fa3, fbl, acc3, 0, 0, 0);
  }

  const int col = nbase + w * 16 + (lane & 15);
  const float bias = b2[col];
  const int brow = (lane >> 4) * 4;
#define RO_EPI(ACC, M)                                        \
  {                                                           \
    _Pragma("unroll")                                         \
    for (int q = 0; q < 4; ++q) {                             \
      const int row = mbase + (M) * 16 + brow + q;            \
      cur2[(size_t)row * OUT_F + col] = (ACC)[q] + bias;      \
    }                                                         \
  }
  RO_EPI(acc0, 0)
  RO_EPI(acc1, 1)
  RO_EPI(acc2, 2)
  RO_EPI(acc3, 3)
#undef RO_EPI
}

// ---------------- readout LIF scan (mem2 in registers across t) ----------------
__global__ void k_ro_scan(const float* __restrict__ cur2,   // [T*B][OUT_F]
                          const float* __restrict__ beta,   // [OUT_F]
                          const float* __restrict__ thr,    // [OUT_F]
                          float* __restrict__ out) {        // [T][B][OUT_F]
  const int i = blockIdx.x * blockDim.x + threadIdx.x;  // b*OUT_F + o
  const int b = i >> 9;
  const int o = i & (OUT_F - 1);
  const float bt = beta[o];
  const float th = thr[o];
  float m = 0.0f;
  for (int t = 0; t < T_STEPS; ++t) {
    const size_t idx = (size_t)(t * BATCH + b) * OUT_F + o;
    m = m - bt + cur2[idx];
    const float s = (m > th) ? 1.0f : 0.0f;  // no relu in readout
    m -= s * th;
    out[idx] = s;
  }
}

// ---------------- launch ----------------
extern "C" void kernel_launch(void* const* d_in, const int* in_sizes, int n_in,
                              void* d_out, int out_size, void* d_ws, size_t ws_size,
                              hipStream_t stream) {
  const float* x        = (const float*)d_in[0];
  const float* w1       = (const float*)d_in[1];
  const float* w2       = (const float*)d_in[2];
  const float* b2       = (const float*)d_in[3];
  const float* beta_lsm = (const float*)d_in[4];
  const float* thr_lsm  = (const float*)d_in[5];
  const float* beta_ro  = (const float*)d_in[6];
  const float* thr_ro   = (const float*)d_in[7];
  float* out = (float*)d_out;

  char* ws = (char*)d_ws;
  size_t off = 0;
  auto alloc = [&](size_t bytes) -> char* {
    char* p = ws + off;
    off += (bytes + 255) & ~(size_t)255;
    return p;
  };
  __hip_bfloat16* w1hi = (__hip_bfloat16*)alloc((size_t)HID * TOTAL * 2);
  __hip_bfloat16* w1lo = (__hip_bfloat16*)alloc((size_t)HID * TOTAL * 2);
  __hip_bfloat16* xb   = (__hip_bfloat16*)alloc((size_t)T_STEPS * BATCH * IN_F * 2);
  __hip_bfloat16* spk  = (__hip_bfloat16*)alloc((size_t)(T_STEPS + 1) * BATCH * HID * 2);
  __hip_bfloat16* w2hi = (__hip_bfloat16*)alloc((size_t)OUT_F * HID * 2);
  __hip_bfloat16* w2lo = (__hip_bfloat16*)alloc((size_t)OUT_F * HID * 2);
  float* mem1 = (float*)alloc((size_t)BATCH * HID * 4);
  float* cur2 = (float*)alloc((size_t)T_STEPS * BATCH * OUT_F * 4);

  // prep
  {
    int n4 = HID * TOTAL / 4;
    k_cvt_split<<<(n4 + 255) / 256, 256, 0, stream>>>(w1, w1hi, w1lo, n4);
  }
  {
    int n4 = OUT_F * HID / 4;
    k_cvt_split<<<(n4 + 255) / 256, 256, 0, stream>>>(w2, w2hi, w2lo, n4);
  }
  {
    int n = T_STEPS * BATCH * IN_F;
    k_cvt_x<<<(n + 255) / 256, 256, 0, stream>>>(x, xb, n);
  }
  {
    int n = BATCH * HID;
    k_zero<<<(n + 255) / 256, 256, 0, stream>>>(mem1, (ushort*)spk, n);
  }

  // sequential reservoir steps
  for (int t = 0; t < T_STEPS; ++t) {
    k_lsm_step<<<HID / 64, 256, 0, stream>>>(t, xb, spk, w1hi, w1lo, mem1,
                                             beta_lsm, thr_lsm);
  }

  // readout
  k_ro_gemm<<<(T_STEPS * BATCH / 64) * (OUT_F / 64), 256, 0, stream>>>(
      spk + (size_t)BATCH * HID, w2hi, w2lo, b2, cur2);
  k_ro_scan<<<(BATCH * OUT_F) / 256, 256, 0, stream>>>(cur2, beta_ro, thr_ro, out);
}